// Round 5
// baseline (5690.712 us; speedup 1.0000x reference)
//
#include <hip/hip_runtime.h>
#include <hip/hip_fp16.h>

// LSTM: B=128, T=1024, H=768, C=256.
// Round 5: dual-mechanism XCD-local barrier.
//  - Arrive (tid0, after store-draining __syncthreads): plain flag store
//    (lands in local XCD L2) + relaxed sc1 fetch_add (MALL, proven round 3).
//  - Wait: poll 32 flags with `sc0 nt` loads (no L1 allocate -> can't spin on
//    a stale L1 line; r4's failure mode) + s_sleep backoff. If FLAG_CAP trips,
//    latch s_heavy and poll the sc1 MALL counter (round-3 proven) forever on.
//  - Data: A-frags direct from L2 (sc0 nt, 24-load batch), no LDS staging.
// Safe fallback for impure grouping = round-1/3 acq/rel barrier + LDS staging.

#define B_ 128
#define T_ 1024
#define H_ 768
#define C_ 256

typedef _Float16 f16;
typedef _Float16 f16x8 __attribute__((ext_vector_type(8)));
typedef float f32x4 __attribute__((ext_vector_type(4)));

#define SPIN_CAP 3000000u
#define FLAG_CAP 60000u

__device__ __forceinline__ float sigm_f(float x) {
  return 1.0f / (1.0f + exp2f(-1.4426950408889634f * x));
}
__device__ __forceinline__ float tanh_f(float x) {
  float ax = fabsf(x);
  float e = exp2f(-2.8853900817779268f * ax);   // e^{-2|x|}
  float t = (1.0f - e) / (1.0f + e);
  return copysignf(t, x);
}

__global__ __launch_bounds__(384, 2) void lstm_main(
    const float* __restrict__ x,      // [128][1024]
    const float* __restrict__ w_in,   // [3072]  (W_ih[:,0])
    const float* __restrict__ W_hh,   // [3072][768]
    const float* __restrict__ b_ih,   // [3072]
    const float* __restrict__ b_hh,   // [3072]
    const float* __restrict__ fc_b,   // [256]
    float* __restrict__ out,          // [128][1024][256]
    f16* __restrict__ hbuf,           // [2][128][768]
    const f16* __restrict__ fcWh,     // [256][768] fp16
    f16* __restrict__ c_hist,         // [1024][128][768] fp16
    unsigned* __restrict__ bar)       // [0..7]=pool [15]=reg [32+g*32]=hctr [512+g*16(+8)]=safe [768+g*32+r]=flags
{
  __shared__ float4 h_s4[1536];                 // safe-mode staging only
  __shared__ __align__(16) float gbuf[6 * 320]; // per-wave 16x20 fp32 regather
  __shared__ int s_g, s_r, s_mode, s_dead, s_heavy;
  char* h_s = (char*)h_s4;

  const int tid = threadIdx.x;
  const int w   = tid >> 6;
  const int l   = tid & 63;
  const int bid = blockIdx.x;

  // ---- registration: group = physical XCD ----
  if (tid == 0) {
    s_dead = 0;
    s_heavy = 0;
    unsigned xcc;
    asm volatile("s_getreg_b32 %0, hwreg(20, 0, 32)" : "=s"(xcc));
    xcc &= 7u;
    unsigned slot = atomicAdd(&bar[xcc], 1u);
    s_g = (int)xcc;
    s_r = (int)(slot & 31u);
    int bad = (slot >= 32u) ? 1 : 0;
    __threadfence();
    atomicAdd(&bar[15], 1u);
    unsigned it = 0;
    while (__hip_atomic_load(&bar[15], __ATOMIC_ACQUIRE, __HIP_MEMORY_SCOPE_AGENT) < 256u) {
      __builtin_amdgcn_s_sleep(2);
      if (++it > SPIN_CAP) { bad = 1; break; }
    }
    __threadfence();
#pragma unroll
    for (int i2 = 0; i2 < 8; ++i2)
      if (__hip_atomic_load(&bar[i2], __ATOMIC_RELAXED, __HIP_MEMORY_SCOPE_AGENT) != 32u) bad = 1;
    s_mode = bad;
  }
  __syncthreads();
  const int mode = s_mode;
  int g, r;
  if (mode) { g = bid & 7; r = bid >> 3; } else { g = s_g; r = s_r; }

  const int bg  = g * 16;
  const int J0  = r * 24;
  const int n   = l & 15;
  const int hi  = l >> 4;

  const int jl  = n >> 2, tau = n & 3;
  const int jp_n = J0 + (w << 2) + jl;
  const float* wr = W_hh + (size_t)(tau * H_ + jp_n) * H_;

  f16x8 wfrag[24];
#pragma unroll
  for (int ks = 0; ks < 24; ++ks) {
    const int k0 = ks * 32 + hi * 8;
    f16x8 f;
#pragma unroll
    for (int e = 0; e < 8; ++e) f[e] = (f16)wr[k0 + e];
    wfrag[ks] = f;
  }

  const int b_own = l & 15;
  const int jj    = hi;
  const int jp_own = J0 + (w << 2) + jj;
  float win4[4], bias4[4];
#pragma unroll
  for (int t4 = 0; t4 < 4; ++t4) {
    const int row = t4 * H_ + jp_own;
    win4[t4]  = w_in[row];
    bias4[t4] = b_ih[row] + b_hh[row];
  }
  const float* xrow = x + (size_t)(bg + b_own) * T_;

  float c = 0.0f;
  float* gw = gbuf + w * 320;
  unsigned* hctr = bar + 32 + g * 32;            // MALL counter (sc1, proven)
  unsigned* fl   = bar + 768 + g * 32;           // 32 flags (local L2)
  unsigned* ctr  = bar + 512 + g * 16;           // safe barrier
  unsigned* gen  = bar + 512 + g * 16 + 8;

  if (!mode) {
    // ================= FAST PATH =================
    const int p = l & 31;                        // flag this lane polls
    for (int t = 0; t < T_; ++t) {
      // ---- wait: all 32 producers done with step t-1 ----
      int heavy = s_heavy;
      if (!heavy) {
        unsigned it = 0;
        for (;;) {
          unsigned v;
          asm volatile("global_load_dword %0, %1, off sc0 nt\n\t"
                       "s_waitcnt vmcnt(0)"
                       : "=v"(v) : "v"(fl + p) : "memory");
          if (__all((int)(v >= (unsigned)t))) break;
          __builtin_amdgcn_s_sleep(1);
          if (++it > FLAG_CAP) { s_heavy = 1; heavy = 1; break; }
        }
      }
      if (heavy) {
        const unsigned tgt = 32u * (unsigned)t;
        unsigned it = 0;
        while (__hip_atomic_load(hctr, __ATOMIC_RELAXED, __HIP_MEMORY_SCOPE_AGENT) < tgt) {
          __builtin_amdgcn_s_sleep(1);
          if (++it > SPIN_CAP) { s_dead = 1; break; }
        }
      }

      // ---- load 24 A-frags from local L2 (sc0 nt: no L1 allocate) ----
      const f16* hsrc = hbuf + (size_t)(t & 1) * (B_ * H_) + (size_t)bg * H_;
      const f16* hp = hsrc + (l & 15) * H_ + hi * 8;
      f16x8 A[24];
      asm volatile(
        "global_load_dwordx4 %0,  %24, off sc0 nt\n\t"
        "global_load_dwordx4 %1,  %24, off offset:64 sc0 nt\n\t"
        "global_load_dwordx4 %2,  %24, off offset:128 sc0 nt\n\t"
        "global_load_dwordx4 %3,  %24, off offset:192 sc0 nt\n\t"
        "global_load_dwordx4 %4,  %24, off offset:256 sc0 nt\n\t"
        "global_load_dwordx4 %5,  %24, off offset:320 sc0 nt\n\t"
        "global_load_dwordx4 %6,  %24, off offset:384 sc0 nt\n\t"
        "global_load_dwordx4 %7,  %24, off offset:448 sc0 nt\n\t"
        "global_load_dwordx4 %8,  %24, off offset:512 sc0 nt\n\t"
        "global_load_dwordx4 %9,  %24, off offset:576 sc0 nt\n\t"
        "global_load_dwordx4 %10, %24, off offset:640 sc0 nt\n\t"
        "global_load_dwordx4 %11, %24, off offset:704 sc0 nt\n\t"
        "global_load_dwordx4 %12, %24, off offset:768 sc0 nt\n\t"
        "global_load_dwordx4 %13, %24, off offset:832 sc0 nt\n\t"
        "global_load_dwordx4 %14, %24, off offset:896 sc0 nt\n\t"
        "global_load_dwordx4 %15, %24, off offset:960 sc0 nt\n\t"
        "global_load_dwordx4 %16, %24, off offset:1024 sc0 nt\n\t"
        "global_load_dwordx4 %17, %24, off offset:1088 sc0 nt\n\t"
        "global_load_dwordx4 %18, %24, off offset:1152 sc0 nt\n\t"
        "global_load_dwordx4 %19, %24, off offset:1216 sc0 nt\n\t"
        "global_load_dwordx4 %20, %24, off offset:1280 sc0 nt\n\t"
        "global_load_dwordx4 %21, %24, off offset:1344 sc0 nt\n\t"
        "global_load_dwordx4 %22, %24, off offset:1408 sc0 nt\n\t"
        "global_load_dwordx4 %23, %24, off offset:1472 sc0 nt"
        : "=&v"(A[0]),  "=&v"(A[1]),  "=&v"(A[2]),  "=&v"(A[3]),
          "=&v"(A[4]),  "=&v"(A[5]),  "=&v"(A[6]),  "=&v"(A[7]),
          "=&v"(A[8]),  "=&v"(A[9]),  "=&v"(A[10]), "=&v"(A[11]),
          "=&v"(A[12]), "=&v"(A[13]), "=&v"(A[14]), "=&v"(A[15]),
          "=&v"(A[16]), "=&v"(A[17]), "=&v"(A[18]), "=&v"(A[19]),
          "=&v"(A[20]), "=&v"(A[21]), "=&v"(A[22]), "=&v"(A[23])
        : "v"(hp) : "memory");
      asm volatile("s_waitcnt vmcnt(0)" ::: "memory");
      __builtin_amdgcn_sched_barrier(0);

      f32x4 acc0 = {0.f, 0.f, 0.f, 0.f}, acc1 = {0.f, 0.f, 0.f, 0.f};
#pragma unroll
      for (int ks = 0; ks < 24; ++ks) {
        if (ks & 1) acc1 = __builtin_amdgcn_mfma_f32_16x16x32_f16(A[ks], wfrag[ks], acc1, 0, 0, 0);
        else        acc0 = __builtin_amdgcn_mfma_f32_16x16x32_f16(A[ks], wfrag[ks], acc0, 0, 0, 0);
      }
      f32x4 acc = acc0 + acc1;

#pragma unroll
      for (int q = 0; q < 4; ++q)
        gw[(hi * 4 + q) * 20 + n] = acc[q];
      float4 gv = *(const float4*)(gw + b_own * 20 + jj * 4);  // i,f,g,o

      const float xt = xrow[t];
      const float gi = gv.x + xt * win4[0] + bias4[0];
      const float gf = gv.y + xt * win4[1] + bias4[1];
      const float gg = gv.z + xt * win4[2] + bias4[2];
      const float go = gv.w + xt * win4[3] + bias4[3];
      c = sigm_f(gf) * c + sigm_f(gi) * tanh_f(gg);
      const float h = sigm_f(go) * tanh_f(c);

      hbuf[(size_t)((t + 1) & 1) * (B_ * H_) + (size_t)(bg + b_own) * H_ + jp_own] = (f16)h;
      c_hist[((size_t)t * B_ + bg + b_own) * H_ + jp_own] = (f16)c;

      __syncthreads();                  // drains vmcnt(0): stores in local L2
      if (s_dead) return;
      if (tid == 0) {
        // arrive both ways: flag (local L2, fast) + counter (MALL, fallback)
        unsigned fv = (unsigned)(t + 1);
        asm volatile("global_store_dword %0, %1, off"
                     :: "v"(fl + r), "v"(fv) : "memory");
        __hip_atomic_fetch_add(hctr, 1u, __ATOMIC_RELAXED, __HIP_MEMORY_SCOPE_AGENT);
      }
    }

    // ---- FC gate: all producers' c_hist complete ----
    {
      int heavy = s_heavy;
      if (!heavy) {
        unsigned it = 0;
        for (;;) {
          unsigned v;
          asm volatile("global_load_dword %0, %1, off sc0 nt\n\t"
                       "s_waitcnt vmcnt(0)"
                       : "=v"(v) : "v"(fl + p) : "memory");
          if (__all((int)(v >= (unsigned)T_))) break;
          __builtin_amdgcn_s_sleep(1);
          if (++it > FLAG_CAP) { heavy = 1; break; }
        }
      }
      if (heavy) {
        unsigned it = 0;
        while (__hip_atomic_load(hctr, __ATOMIC_RELAXED, __HIP_MEMORY_SCOPE_AGENT) < 32u * (unsigned)T_) {
          __builtin_amdgcn_s_sleep(1);
          if (++it > SPIN_CAP) { return; }
        }
      }
    }
  } else {
    // ================= SAFE PATH (round-3 proven) =================
    for (int t = 0; t < T_; ++t) {
      const f16* hsrc = hbuf + (size_t)(t & 1) * (B_ * H_) + (size_t)bg * H_;
#pragma unroll
      for (int s = 0; s < 4; ++s) {
        const int ci = tid + 384 * s;
        const int bb = ci / 96, ck = ci - bb * 96;
        float4 v = *(const float4*)(hsrc + bb * H_ + ck * 8);
        *(float4*)(h_s + bb * 1536 + ((ck ^ (bb & 7)) << 4)) = v;
      }
      __syncthreads();

      f32x4 acc0 = {0.f, 0.f, 0.f, 0.f}, acc1 = {0.f, 0.f, 0.f, 0.f};
#pragma unroll
      for (int ks = 0; ks < 24; ++ks) {
        f16x8 a = *(const f16x8*)(h_s + (l & 15) * 1536 +
                                  ((((ks << 2) + hi) ^ (l & 7)) << 4));
        if (ks & 1) acc1 = __builtin_amdgcn_mfma_f32_16x16x32_f16(a, wfrag[ks], acc1, 0, 0, 0);
        else        acc0 = __builtin_amdgcn_mfma_f32_16x16x32_f16(a, wfrag[ks], acc0, 0, 0, 0);
      }
      f32x4 acc = acc0 + acc1;

#pragma unroll
      for (int q = 0; q < 4; ++q)
        gw[(hi * 4 + q) * 20 + n] = acc[q];
      float4 gv = *(const float4*)(gw + b_own * 20 + jj * 4);

      const float xt = xrow[t];
      const float gi = gv.x + xt * win4[0] + bias4[0];
      const float gf = gv.y + xt * win4[1] + bias4[1];
      const float gg = gv.z + xt * win4[2] + bias4[2];
      const float go = gv.w + xt * win4[3] + bias4[3];
      c = sigm_f(gf) * c + sigm_f(gi) * tanh_f(gg);
      const float h = sigm_f(go) * tanh_f(c);

      hbuf[(size_t)((t + 1) & 1) * (B_ * H_) + (size_t)(bg + b_own) * H_ + jp_own] = (f16)h;
      c_hist[((size_t)t * B_ + bg + b_own) * H_ + jp_own] = (f16)c;

      __syncthreads();
      if (tid == 0) {
        __threadfence();
        unsigned g0 = __hip_atomic_load(gen, __ATOMIC_ACQUIRE, __HIP_MEMORY_SCOPE_AGENT);
        unsigned a  = __hip_atomic_fetch_add(ctr, 1u, __ATOMIC_ACQ_REL, __HIP_MEMORY_SCOPE_AGENT);
        if (a == 31u) {
          __hip_atomic_store(ctr, 0u, __ATOMIC_RELAXED, __HIP_MEMORY_SCOPE_AGENT);
          __hip_atomic_fetch_add(gen, 1u, __ATOMIC_RELEASE, __HIP_MEMORY_SCOPE_AGENT);
        } else {
          unsigned it = 0;
          while (__hip_atomic_load(gen, __ATOMIC_ACQUIRE, __HIP_MEMORY_SCOPE_AGENT) == g0) {
            __builtin_amdgcn_s_sleep(1);
            if (++it > SPIN_CAP) { s_dead = 1; break; }
          }
        }
        __threadfence();
      }
      __syncthreads();
      if (s_dead) return;
    }
  }

  // ---- FC: out[b,t,:] = c_t[b,:] @ fcW^T + fc_b (per group) ----
  for (int ti = w; ti < 32; ti += 6) {
    const int tt = r + 32 * ti;
    const f16* ar = c_hist + ((size_t)tt * B_ + bg + n) * H_;
    const f16* ab = ar + hi * 8;
    f16x8 afrag[24];
    if (!mode) {
#pragma unroll
      for (int kg = 0; kg < 3; ++kg) {
        asm volatile(
          "global_load_dwordx4 %0, %8, off sc0 nt\n\t"
          "global_load_dwordx4 %1, %8, off offset:64 sc0 nt\n\t"
          "global_load_dwordx4 %2, %8, off offset:128 sc0 nt\n\t"
          "global_load_dwordx4 %3, %8, off offset:192 sc0 nt\n\t"
          "global_load_dwordx4 %4, %8, off offset:256 sc0 nt\n\t"
          "global_load_dwordx4 %5, %8, off offset:320 sc0 nt\n\t"
          "global_load_dwordx4 %6, %8, off offset:384 sc0 nt\n\t"
          "global_load_dwordx4 %7, %8, off offset:448 sc0 nt\n\t"
          "s_waitcnt vmcnt(0)"
          : "=&v"(afrag[kg * 8 + 0]), "=&v"(afrag[kg * 8 + 1]),
            "=&v"(afrag[kg * 8 + 2]), "=&v"(afrag[kg * 8 + 3]),
            "=&v"(afrag[kg * 8 + 4]), "=&v"(afrag[kg * 8 + 5]),
            "=&v"(afrag[kg * 8 + 6]), "=&v"(afrag[kg * 8 + 7])
          : "v"(ab + kg * 256)
          : "memory");
      }
    } else {
#pragma unroll
      for (int ks = 0; ks < 24; ++ks)
        afrag[ks] = *(const f16x8*)(ar + ks * 32 + hi * 8);
    }
    for (int nt2 = 0; nt2 < 16; ++nt2) {
      f32x4 fa = {0.f, 0.f, 0.f, 0.f};
      const f16* br = fcWh + (size_t)(nt2 * 16 + n) * H_;
#pragma unroll
      for (int ks = 0; ks < 24; ++ks) {
        f16x8 bfr = *(const f16x8*)(br + ks * 32 + hi * 8);
        fa = __builtin_amdgcn_mfma_f32_16x16x32_f16(afrag[ks], bfr, fa, 0, 0, 0);
      }
      const float fb = fc_b[nt2 * 16 + n];
      float* ob = out + (size_t)tt * C_ + nt2 * 16 + n;
#pragma unroll
      for (int q = 0; q < 4; ++q)
        ob[(size_t)(bg + hi * 4 + q) * ((size_t)T_ * C_)] = fa[q] + fb;
    }
  }
}

__global__ __launch_bounds__(256) void prep(
    const float* __restrict__ fcW, f16* __restrict__ fcWh,
    f16* __restrict__ hbuf, unsigned* __restrict__ bar)
{
  const int i = blockIdx.x * 256 + threadIdx.x;
  const int nth = gridDim.x * 256;
  for (int k = i; k < C_ * H_; k += nth) fcWh[k] = (f16)fcW[k];
  for (int k = i; k < 2 * B_ * H_; k += nth) hbuf[k] = (f16)0.0f;
  if (i < 1024) bar[i] = 0u;
}

extern "C" void kernel_launch(void* const* d_in, const int* in_sizes, int n_in,
                              void* d_out, int out_size, void* d_ws, size_t ws_size,
                              hipStream_t stream) {
  const float* x   = (const float*)d_in[0];
  const float* Wih = (const float*)d_in[1];
  const float* Whh = (const float*)d_in[2];
  const float* bih = (const float*)d_in[3];
  const float* bhh = (const float*)d_in[4];
  const float* fcW = (const float*)d_in[5];
  const float* fcb = (const float*)d_in[6];
  float* out = (float*)d_out;

  char* ws = (char*)d_ws;
  f16* hbuf      = (f16*)ws;                   // 393216 B
  f16* fcWh      = (f16*)(ws + 393216);        // 393216 B
  unsigned* bar  = (unsigned*)(ws + 786432);   // 4096 B
  f16* c_hist    = (f16*)(ws + (1 << 20));     // 201326592 B
  const size_t need = (size_t)(1 << 20) + 201326592ull;
  if (ws_size < need) {
    hipMemsetAsync(d_out, 0, (size_t)out_size * 4, stream);
    return;
  }

  hipLaunchKernelGGL(prep, dim3(256), dim3(256), 0, stream, fcW, fcWh, hbuf, bar);

  void* args[] = { (void*)&x, (void*)&Wih, (void*)&Whh, (void*)&bih, (void*)&bhh,
                   (void*)&fcb, (void*)&out, (void*)&hbuf, (void*)&fcWh,
                   (void*)&c_hist, (void*)&bar };
  hipLaunchCooperativeKernel((void*)lstm_main, dim3(256), dim3(384), args, 0, stream);
}

// Round 7
// 2395.442 us; speedup vs baseline: 2.3756x; 2.3756x over previous
//
#include <hip/hip_runtime.h>
#include <hip/hip_fp16.h>

// LSTM: B=128, T=1024, H=768, C=256.
// Round 7: r6 structure + the PROVEN poll flavor.
// Evidence ledger: poll sc0 -> stale-L1 spin, dead (r4, r6); poll sc0 nt ->
// live (r5; timing rules out its fallback having engaged). Plain flag stores
// land in local XCD L2 and are visible to nt loads (r5). So:
//  - Stage h once/block into LDS (sc0 nt batch loads, XOR swizzle).
//  - tid0 plain-stores flag[r]=t+1 after the drain barrier; wave0 ONLY polls
//    32 flags with sc0 nt + check-then-sleep; other waves park at s_barrier.
//  - h/c stores shuffle-packed: lanes 0-15 store one dwordx2 per buffer.
//  - All streaming global reads sc0 nt (no L1-eviction luck anywhere).
// Watchdogs fail fast. Safe fallback (impure pools) = round-3 proven barrier.

#define B_ 128
#define T_ 1024
#define H_ 768
#define C_ 256

typedef _Float16 f16;
typedef _Float16 f16x8 __attribute__((ext_vector_type(8)));
typedef float f32x4 __attribute__((ext_vector_type(4)));

#define SPIN_CAP 3000000u
#define FLAG_CAP 1000000u

__device__ __forceinline__ float sigm_f(float x) {
  return 1.0f / (1.0f + exp2f(-1.4426950408889634f * x));
}
__device__ __forceinline__ float tanh_f(float x) {
  float ax = fabsf(x);
  float e = exp2f(-2.8853900817779268f * ax);   // e^{-2|x|}
  float t = (1.0f - e) / (1.0f + e);
  return copysignf(t, x);
}
__device__ __forceinline__ unsigned pk2(float a, float b) {
  f16 ha = (f16)a, hb = (f16)b;
  unsigned short ua = __builtin_bit_cast(unsigned short, ha);
  unsigned short ub = __builtin_bit_cast(unsigned short, hb);
  return (unsigned)ua | ((unsigned)ub << 16);
}

__global__ __launch_bounds__(384, 2) void lstm_main(
    const float* __restrict__ x,      // [128][1024]
    const float* __restrict__ w_in,   // [3072]  (W_ih[:,0])
    const float* __restrict__ W_hh,   // [3072][768]
    const float* __restrict__ b_ih,   // [3072]
    const float* __restrict__ b_hh,   // [3072]
    const float* __restrict__ fc_b,   // [256]
    float* __restrict__ out,          // [128][1024][256]
    f16* __restrict__ hbuf,           // [2][128][768]
    const f16* __restrict__ fcWh,     // [256][768] fp16
    f16* __restrict__ c_hist,         // [1024][128][768] fp16
    unsigned* __restrict__ bar)       // [0..7]=pool [15]=reg [512+g*16(+8)]=safe [768+g*32+r]=flags
{
  __shared__ float4 h_s4[1536];                 // 16 x 768 fp16, swizzled
  __shared__ __align__(16) float gbuf[6 * 320]; // per-wave 16x20 fp32 regather
  __shared__ int s_g, s_r, s_mode, s_dead;
  char* h_s = (char*)h_s4;

  const int tid = threadIdx.x;
  const int w   = tid >> 6;
  const int l   = tid & 63;
  const int bid = blockIdx.x;

  // ---- registration: group = physical XCD ----
  if (tid == 0) {
    s_dead = 0;
    unsigned xcc;
    asm volatile("s_getreg_b32 %0, hwreg(20, 0, 32)" : "=s"(xcc));
    xcc &= 7u;
    unsigned slot = atomicAdd(&bar[xcc], 1u);
    s_g = (int)xcc;
    s_r = (int)(slot & 31u);
    int bad = (slot >= 32u) ? 1 : 0;
    __threadfence();
    atomicAdd(&bar[15], 1u);
    unsigned it = 0;
    while (__hip_atomic_load(&bar[15], __ATOMIC_ACQUIRE, __HIP_MEMORY_SCOPE_AGENT) < 256u) {
      __builtin_amdgcn_s_sleep(2);
      if (++it > SPIN_CAP) { bad = 1; break; }
    }
    __threadfence();
#pragma unroll
    for (int i2 = 0; i2 < 8; ++i2)
      if (__hip_atomic_load(&bar[i2], __ATOMIC_RELAXED, __HIP_MEMORY_SCOPE_AGENT) != 32u) bad = 1;
    s_mode = bad;
  }
  __syncthreads();
  const int mode = s_mode;
  int g, r;
  if (mode) { g = bid & 7; r = bid >> 3; } else { g = s_g; r = s_r; }

  const int bg  = g * 16;
  const int J0  = r * 24;
  const int n   = l & 15;
  const int hi  = l >> 4;

  const int jl  = n >> 2, tau = n & 3;
  const int jp_n = J0 + (w << 2) + jl;
  const float* wr = W_hh + (size_t)(tau * H_ + jp_n) * H_;

  // Persistent W_hh fragments (fp16), 96 VGPR/lane
  f16x8 wfrag[24];
#pragma unroll
  for (int ks = 0; ks < 24; ++ks) {
    const int k0 = ks * 32 + hi * 8;
    f16x8 f;
#pragma unroll
    for (int e = 0; e < 8; ++e) f[e] = (f16)wr[k0 + e];
    wfrag[ks] = f;
  }

  const int b_own = l & 15;
  const int jj    = hi;
  const int jp_own = J0 + (w << 2) + jj;
  float win4[4], bias4[4];
#pragma unroll
  for (int t4 = 0; t4 < 4; ++t4) {
    const int row = t4 * H_ + jp_own;
    win4[t4]  = w_in[row];
    bias4[t4] = b_ih[row] + b_hh[row];
  }
  const float* xrow = x + (size_t)(bg + b_own) * T_;

  float c = 0.0f;
  float* gw = gbuf + w * 320;
  unsigned* fl   = bar + 768 + g * 32;           // 32 flags (local XCD L2)
  unsigned* ctr  = bar + 512 + g * 16;           // safe barrier
  unsigned* gen  = bar + 512 + g * 16 + 8;

  if (!mode) {
    // ================= FAST PATH =================
    const int p = l & 31;
    for (int t = 0; t < T_; ++t) {
      // ---- stage h_t (hbuf[t&1]) into LDS, XOR-swizzled, sc0 nt ----
      const f16* hsrc = hbuf + (size_t)(t & 1) * (B_ * H_) + (size_t)bg * H_;
      const float* gp[4]; int ldst[4]; float4 gv4[4];
#pragma unroll
      for (int s = 0; s < 4; ++s) {
        const int ci = tid + 384 * s;
        const int bb = ci / 96, ck = ci - bb * 96;
        gp[s]   = (const float*)(hsrc + bb * H_ + ck * 8);
        ldst[s] = bb * 1536 + ((ck ^ (bb & 7)) << 4);
      }
      asm volatile(
        "global_load_dwordx4 %0, %4, off sc0 nt\n\t"
        "global_load_dwordx4 %1, %5, off sc0 nt\n\t"
        "global_load_dwordx4 %2, %6, off sc0 nt\n\t"
        "global_load_dwordx4 %3, %7, off sc0 nt\n\t"
        "s_waitcnt vmcnt(0)"
        : "=&v"(gv4[0]), "=&v"(gv4[1]), "=&v"(gv4[2]), "=&v"(gv4[3])
        : "v"(gp[0]), "v"(gp[1]), "v"(gp[2]), "v"(gp[3])
        : "memory");
#pragma unroll
      for (int s = 0; s < 4; ++s) *(float4*)(h_s + ldst[s]) = gv4[s];
      __syncthreads();                            // (#1) LDS tile ready

      // ---- gates = h @ W^T : 24 MFMA ----
      f32x4 acc0 = {0.f, 0.f, 0.f, 0.f}, acc1 = {0.f, 0.f, 0.f, 0.f};
#pragma unroll
      for (int ks = 0; ks < 24; ++ks) {
        f16x8 a = *(const f16x8*)(h_s + (l & 15) * 1536 +
                                  ((((ks << 2) + hi) ^ (l & 7)) << 4));
        if (ks & 1) acc1 = __builtin_amdgcn_mfma_f32_16x16x32_f16(a, wfrag[ks], acc1, 0, 0, 0);
        else        acc0 = __builtin_amdgcn_mfma_f32_16x16x32_f16(a, wfrag[ks], acc0, 0, 0, 0);
      }
      f32x4 acc = acc0 + acc1;

      // ---- wave-local regather (per-wave LDS, lgkm-ordered) ----
#pragma unroll
      for (int q = 0; q < 4; ++q)
        gw[(hi * 4 + q) * 20 + n] = acc[q];
      float4 gv = *(const float4*)(gw + b_own * 20 + jj * 4);  // i,f,g,o

      // ---- pointwise ----
      const float xt = xrow[t];
      const float gi = gv.x + xt * win4[0] + bias4[0];
      const float gf = gv.y + xt * win4[1] + bias4[1];
      const float gg = gv.z + xt * win4[2] + bias4[2];
      const float go = gv.w + xt * win4[3] + bias4[3];
      c = sigm_f(gf) * c + sigm_f(gi) * tanh_f(gg);
      const float h = sigm_f(go) * tanh_f(c);

      // ---- shuffle-pack h,c: lanes 0-15 store one dwordx2 per buffer ----
      const float h1 = __shfl_down(h, 16, 64);
      const float h2 = __shfl_down(h, 32, 64);
      const float h3 = __shfl_down(h, 48, 64);
      const float c1 = __shfl_down(c, 16, 64);
      const float c2 = __shfl_down(c, 32, 64);
      const float c3 = __shfl_down(c, 48, 64);
      if (l < 16) {
        uint2 hp2, cp2;
        hp2.x = pk2(h,  h1); hp2.y = pk2(h2, h3);
        cp2.x = pk2(c,  c1); cp2.y = pk2(c2, c3);
        *(uint2*)(hbuf + (size_t)((t + 1) & 1) * (B_ * H_) +
                  (size_t)(bg + l) * H_ + J0 + 4 * w) = hp2;
        *(uint2*)(c_hist + ((size_t)t * B_ + bg + l) * H_ + J0 + 4 * w) = cp2;
      }

      __syncthreads();                            // (#2) all stores drained to local L2
      if (tid == 0) {
        unsigned fv = (unsigned)(t + 1);
        asm volatile("global_store_dword %0, %1, off"
                     :: "v"(fl + r), "v"(fv) : "memory");
      }
      if (w == 0) {                               // wave0 polls (nt!); others park at (#3)
        unsigned it = 0;
        for (;;) {
          unsigned v;
          asm volatile("global_load_dword %0, %1, off sc0 nt\n\t"
                       "s_waitcnt vmcnt(0)"
                       : "=v"(v) : "v"(fl + p) : "memory");
          if (__all((int)(v >= (unsigned)(t + 1)))) break;
          __builtin_amdgcn_s_sleep(1);
          if (++it > FLAG_CAP) { s_dead = 1; break; }
        }
      }
      __syncthreads();                            // (#3) release
      if (s_dead) return;
    }
  } else {
    // ================= SAFE PATH (round-3 proven) =================
    for (int t = 0; t < T_; ++t) {
      const f16* hsrc = hbuf + (size_t)(t & 1) * (B_ * H_) + (size_t)bg * H_;
#pragma unroll
      for (int s = 0; s < 4; ++s) {
        const int ci = tid + 384 * s;
        const int bb = ci / 96, ck = ci - bb * 96;
        float4 v = *(const float4*)(hsrc + bb * H_ + ck * 8);
        *(float4*)(h_s + bb * 1536 + ((ck ^ (bb & 7)) << 4)) = v;
      }
      __syncthreads();

      f32x4 acc0 = {0.f, 0.f, 0.f, 0.f}, acc1 = {0.f, 0.f, 0.f, 0.f};
#pragma unroll
      for (int ks = 0; ks < 24; ++ks) {
        f16x8 a = *(const f16x8*)(h_s + (l & 15) * 1536 +
                                  ((((ks << 2) + hi) ^ (l & 7)) << 4));
        if (ks & 1) acc1 = __builtin_amdgcn_mfma_f32_16x16x32_f16(a, wfrag[ks], acc1, 0, 0, 0);
        else        acc0 = __builtin_amdgcn_mfma_f32_16x16x32_f16(a, wfrag[ks], acc0, 0, 0, 0);
      }
      f32x4 acc = acc0 + acc1;

#pragma unroll
      for (int q = 0; q < 4; ++q)
        gw[(hi * 4 + q) * 20 + n] = acc[q];
      float4 gv = *(const float4*)(gw + b_own * 20 + jj * 4);

      const float xt = xrow[t];
      const float gi = gv.x + xt * win4[0] + bias4[0];
      const float gf = gv.y + xt * win4[1] + bias4[1];
      const float gg = gv.z + xt * win4[2] + bias4[2];
      const float go = gv.w + xt * win4[3] + bias4[3];
      c = sigm_f(gf) * c + sigm_f(gi) * tanh_f(gg);
      const float h = sigm_f(go) * tanh_f(c);

      hbuf[(size_t)((t + 1) & 1) * (B_ * H_) + (size_t)(bg + b_own) * H_ + jp_own] = (f16)h;
      c_hist[((size_t)t * B_ + bg + b_own) * H_ + jp_own] = (f16)c;

      __syncthreads();
      if (tid == 0) {
        __threadfence();
        unsigned g0 = __hip_atomic_load(gen, __ATOMIC_ACQUIRE, __HIP_MEMORY_SCOPE_AGENT);
        unsigned a  = __hip_atomic_fetch_add(ctr, 1u, __ATOMIC_ACQ_REL, __HIP_MEMORY_SCOPE_AGENT);
        if (a == 31u) {
          __hip_atomic_store(ctr, 0u, __ATOMIC_RELAXED, __HIP_MEMORY_SCOPE_AGENT);
          __hip_atomic_fetch_add(gen, 1u, __ATOMIC_RELEASE, __HIP_MEMORY_SCOPE_AGENT);
        } else {
          unsigned it = 0;
          while (__hip_atomic_load(gen, __ATOMIC_ACQUIRE, __HIP_MEMORY_SCOPE_AGENT) == g0) {
            __builtin_amdgcn_s_sleep(1);
            if (++it > SPIN_CAP) { s_dead = 1; break; }
          }
        }
        __threadfence();
      }
      __syncthreads();
      if (s_dead) return;
    }
  }

  // ---- FC: out[b,t,:] = c_t[b,:] @ fcW^T + fc_b (per group) ----
  for (int ti = w; ti < 32; ti += 6) {
    const int tt = r + 32 * ti;
    const f16* ar = c_hist + ((size_t)tt * B_ + bg + n) * H_;
    const f16* ab = ar + hi * 8;
    f16x8 afrag[24];
    if (!mode) {
#pragma unroll
      for (int kg = 0; kg < 3; ++kg) {
        asm volatile(
          "global_load_dwordx4 %0, %8, off sc0 nt\n\t"
          "global_load_dwordx4 %1, %8, off offset:64 sc0 nt\n\t"
          "global_load_dwordx4 %2, %8, off offset:128 sc0 nt\n\t"
          "global_load_dwordx4 %3, %8, off offset:192 sc0 nt\n\t"
          "global_load_dwordx4 %4, %8, off offset:256 sc0 nt\n\t"
          "global_load_dwordx4 %5, %8, off offset:320 sc0 nt\n\t"
          "global_load_dwordx4 %6, %8, off offset:384 sc0 nt\n\t"
          "global_load_dwordx4 %7, %8, off offset:448 sc0 nt\n\t"
          "s_waitcnt vmcnt(0)"
          : "=&v"(afrag[kg * 8 + 0]), "=&v"(afrag[kg * 8 + 1]),
            "=&v"(afrag[kg * 8 + 2]), "=&v"(afrag[kg * 8 + 3]),
            "=&v"(afrag[kg * 8 + 4]), "=&v"(afrag[kg * 8 + 5]),
            "=&v"(afrag[kg * 8 + 6]), "=&v"(afrag[kg * 8 + 7])
          : "v"(ab + kg * 256)
          : "memory");
      }
    } else {
#pragma unroll
      for (int ks = 0; ks < 24; ++ks)
        afrag[ks] = *(const f16x8*)(ar + ks * 32 + hi * 8);
    }
    for (int nt2 = 0; nt2 < 16; ++nt2) {
      f32x4 fa = {0.f, 0.f, 0.f, 0.f};
      const f16* br = fcWh + (size_t)(nt2 * 16 + n) * H_;
#pragma unroll
      for (int ks = 0; ks < 24; ++ks) {
        f16x8 bfr = *(const f16x8*)(br + ks * 32 + hi * 8);
        fa = __builtin_amdgcn_mfma_f32_16x16x32_f16(afrag[ks], bfr, fa, 0, 0, 0);
      }
      const float fb = fc_b[nt2 * 16 + n];
      float* ob = out + (size_t)tt * C_ + nt2 * 16 + n;
#pragma unroll
      for (int q = 0; q < 4; ++q)
        ob[(size_t)(bg + hi * 4 + q) * ((size_t)T_ * C_)] = fa[q] + fb;
    }
  }
}

__global__ __launch_bounds__(256) void prep(
    const float* __restrict__ fcW, f16* __restrict__ fcWh,
    f16* __restrict__ hbuf, unsigned* __restrict__ bar)
{
  const int i = blockIdx.x * 256 + threadIdx.x;
  const int nth = gridDim.x * 256;
  for (int k = i; k < C_ * H_; k += nth) fcWh[k] = (f16)fcW[k];
  for (int k = i; k < 2 * B_ * H_; k += nth) hbuf[k] = (f16)0.0f;
  if (i < 1024) bar[i] = 0u;
}

extern "C" void kernel_launch(void* const* d_in, const int* in_sizes, int n_in,
                              void* d_out, int out_size, void* d_ws, size_t ws_size,
                              hipStream_t stream) {
  const float* x   = (const float*)d_in[0];
  const float* Wih = (const float*)d_in[1];
  const float* Whh = (const float*)d_in[2];
  const float* bih = (const float*)d_in[3];
  const float* bhh = (const float*)d_in[4];
  const float* fcW = (const float*)d_in[5];
  const float* fcb = (const float*)d_in[6];
  float* out = (float*)d_out;

  char* ws = (char*)d_ws;
  f16* hbuf      = (f16*)ws;                   // 393216 B
  f16* fcWh      = (f16*)(ws + 393216);        // 393216 B
  unsigned* bar  = (unsigned*)(ws + 786432);   // 4096 B
  f16* c_hist    = (f16*)(ws + (1 << 20));     // 201326592 B
  const size_t need = (size_t)(1 << 20) + 201326592ull;
  if (ws_size < need) {
    hipMemsetAsync(d_out, 0, (size_t)out_size * 4, stream);
    return;
  }

  hipLaunchKernelGGL(prep, dim3(256), dim3(256), 0, stream, fcW, fcWh, hbuf, bar);

  void* args[] = { (void*)&x, (void*)&Wih, (void*)&Whh, (void*)&bih, (void*)&bhh,
                   (void*)&fcb, (void*)&out, (void*)&hbuf, (void*)&fcWh,
                   (void*)&c_hist, (void*)&bar };
  hipLaunchCooperativeKernel((void*)lstm_main, dim3(256), dim3(384), args, 0, stream);
}